// Round 4
// baseline (1160.557 us; speedup 1.0000x reference)
//
#include <hip/hip_runtime.h>
#include <hip/hip_bf16.h>

#define NNODES 40000
#define NEDGE  60000
#define NCYC5  30000
#define NCYC6  25000
#define EROWS  (2*NEDGE)    // 120000
#define C5ROWS (5*NCYC5)    // 150000
#define C6ROWS (6*NCYC6)    // 150000

typedef __attribute__((ext_vector_type(8))) short short8;   // 8 bf16 lanes
typedef __attribute__((ext_vector_type(4))) float f32x4;

__device__ __forceinline__ short f2bs(float x){
  union { __hip_bfloat16 h; short s; } u; u.h = __float2bfloat16(x); return u.s;
}
__device__ __forceinline__ float bs2f(short s){
  union { short s; __hip_bfloat16 h; } u; u.s = s; return __bfloat162float(u.h);
}

// rows m and m^1 live in adjacent lanes (l15 pairs): piece3 = val(m)+val(m^1)
__device__ __forceinline__ short8 combine_pair(short8 a){
  union U { short8 v; int i[4]; } u, w;
  u.v = a;
  #pragma unroll
  for (int j = 0; j < 4; ++j) w.i[j] = __shfl_xor(u.i[j], 1);
  short8 r;
  #pragma unroll
  for (int j = 0; j < 8; ++j) r[j] = f2bs(bs2f(a[j]) + bs2f(w.v[j]));
  return r;
}

// ---------------- CSR build (fused 3-range) ----------------
__global__ void hist3_k(const int* __restrict__ ea, const int* __restrict__ c5a,
                        const int* __restrict__ c6a, int* __restrict__ de,
                        int* __restrict__ d5, int* __restrict__ d6){
  int r = blockIdx.x*256 + threadIdx.x;
  if (r < EROWS)                        atomicAdd(&de[ea[r]], 1);
  else if (r < EROWS + C5ROWS)          atomicAdd(&d5[c5a[r - EROWS]], 1);
  else if (r < EROWS + C5ROWS + C6ROWS) atomicAdd(&d6[c6a[r - EROWS - C5ROWS]], 1);
}

// 3 blocks, 1024 threads each: exclusive scan of one deg array per block
__global__ void scan3_k(const int* __restrict__ d0, const int* __restrict__ d1,
                        const int* __restrict__ d2, int* __restrict__ o0,
                        int* __restrict__ o1, int* __restrict__ o2){
  const int* deg = blockIdx.x==0 ? d0 : (blockIdx.x==1 ? d1 : d2);
  int* offs      = blockIdx.x==0 ? o0 : (blockIdx.x==1 ? o1 : o2);
  const int N = NNODES;
  __shared__ int part[1024];
  int tid = threadIdx.x;
  const int chunk = (N + 1023) / 1024;
  int lo = tid*chunk, hi = min(lo+chunk, N);
  int s = 0;
  for (int i = lo; i < hi; ++i) s += deg[i];
  part[tid] = s;
  __syncthreads();
  for (int d = 1; d < 1024; d <<= 1){
    int v = (tid >= d) ? part[tid-d] : 0;
    __syncthreads();
    part[tid] += v;
    __syncthreads();
  }
  int pref = (tid == 0) ? 0 : part[tid-1];
  for (int i = lo; i < hi; ++i){ offs[i] = pref; pref += deg[i]; }
  if (tid == 1023) offs[N] = part[1023];
}

__global__ void fill3_k(const int* __restrict__ ea, const int* __restrict__ c5a,
                        const int* __restrict__ c6a,
                        const int* __restrict__ oe, const int* __restrict__ o5,
                        const int* __restrict__ o6,
                        int* __restrict__ cue, int* __restrict__ cu5,
                        int* __restrict__ cu6,
                        int* __restrict__ re, int* __restrict__ r5,
                        int* __restrict__ r6){
  int r = blockIdx.x*256 + threadIdx.x;
  if (r < EROWS){
    int a = ea[r]; re[oe[a] + atomicAdd(&cue[a],1)] = r;
  } else if (r < EROWS + C5ROWS){
    int rr = r - EROWS; int a = c5a[rr]; r5[o5[a] + atomicAdd(&cu5[a],1)] = rr;
  } else if (r < EROWS + C5ROWS + C6ROWS){
    int rr = r - EROWS - C5ROWS; int a = c6a[rr]; r6[o6[a] + atomicAdd(&cu6[a],1)] = rr;
  }
}

// ---------------- fused phase-1 kernels ----------------
// node_e[n][ch] = sum over incident edge rows of edge_feats
__global__ void gne_k(const float* __restrict__ ef, const int* __restrict__ offs,
                      const int* __restrict__ rows, float* __restrict__ node_e){
  int t = blockIdx.x*256 + threadIdx.x;
  if (t >= NNODES*64) return;
  int n = t >> 6, ch = t & 63;
  int o = offs[n], e = offs[n+1];
  float s = 0.f;
  for (int i = o; i < e; ++i) s += ef[(size_t)rows[i]*64 + ch];
  node_e[t] = s;
}

// S1_5[c] = sum_j node_e[atom5[c*5+j]]; S1_6 likewise (one fused launch)
__global__ void s1f_k(const float* __restrict__ node_e,
                      const int* __restrict__ a5, const int* __restrict__ a6,
                      float* __restrict__ S1_5, float* __restrict__ S1_6){
  int t = blockIdx.x*256 + threadIdx.x;
  if (t < NCYC5*64){
    int c = t >> 6, ch = t & 63;
    const int* ap = a5 + c*5;
    float s = 0.f;
    #pragma unroll
    for (int j = 0; j < 5; ++j) s += node_e[(size_t)ap[j]*64 + ch];
    S1_5[t] = s;
  } else if (t < NCYC5*64 + NCYC6*64){
    int t2 = t - NCYC5*64;
    int c = t2 >> 6, ch = t2 & 63;
    const int* ap = a6 + c*6;
    float s = 0.f;
    #pragma unroll
    for (int j = 0; j < 6; ++j) s += node_e[(size_t)ap[j]*64 + ch];
    S1_6[t2] = s;
  }
}

// n5_Xh[n] = [degX(n)*node_e[n] ; sum over CSR_X rows of S1_X[r/R]]
// (replaces n5lo x2 + gath x2; single read of node_e, single write, no RMW)
__global__ void n5f_k(const float* __restrict__ node_e,
                      const int* __restrict__ o5, const int* __restrict__ r5,
                      const int* __restrict__ o6, const int* __restrict__ r6,
                      const float* __restrict__ S1_5, const float* __restrict__ S1_6,
                      short* __restrict__ n5_5h, short* __restrict__ n5_6h){
  int t = blockIdx.x*256 + threadIdx.x;
  if (t >= NNODES*64) return;
  int n = t >> 6, ch = t & 63;
  float v = node_e[t];
  int a5 = o5[n], b5 = o5[n+1], a6 = o6[n], b6 = o6[n+1];
  float s5 = 0.f, s6 = 0.f;
  for (int i = a5; i < b5; ++i) s5 += S1_5[(size_t)(r5[i]/5)*64 + ch];
  for (int i = a6; i < b6; ++i) s6 += S1_6[(size_t)(r6[i]/6)*64 + ch];
  n5_5h[(size_t)n*128 + ch]      = f2bs((float)(b5-a5) * v);
  n5_5h[(size_t)n*128 + 64 + ch] = f2bs(s5);
  n5_6h[(size_t)n*128 + ch]      = f2bs((float)(b6-a6) * v);
  n5_6h[(size_t)n*128 + 64 + ch] = f2bs(s6);
}

// S2_X[c][ch] = sum_j n5_Xh[atomX[c*R+j]][ch]  (fused 5/6)
__global__ void s2f_k(const short* __restrict__ n5_5h, const short* __restrict__ n5_6h,
                      const int* __restrict__ a5, const int* __restrict__ a6,
                      short* __restrict__ S2_5h, short* __restrict__ S2_6h){
  int t = blockIdx.x*256 + threadIdx.x;
  if (t < NCYC5*128){
    int c = t >> 7, ch = t & 127;
    const int* ap = a5 + c*5;
    float s = 0.f;
    #pragma unroll
    for (int j = 0; j < 5; ++j) s += bs2f(n5_5h[(size_t)ap[j]*128 + ch]);
    S2_5h[t] = f2bs(s);
  } else if (t < NCYC5*128 + NCYC6*128){
    int t2 = t - NCYC5*128;
    int c = t2 >> 7, ch = t2 & 127;
    const int* ap = a6 + c*6;
    float s = 0.f;
    #pragma unroll
    for (int j = 0; j < 6; ++j) s += bs2f(n5_6h[(size_t)ap[j]*128 + ch]);
    S2_6h[t2] = f2bs(s);
  }
}

// nodeC[n][0:320] computed in ONE pass (replaces nc0 + 4 RMW gath passes).
__global__ void ncf_k(const short* __restrict__ n5_5h, const short* __restrict__ n5_6h,
                      const int* __restrict__ o5, const int* __restrict__ r5,
                      const int* __restrict__ o6, const int* __restrict__ r6,
                      const short* __restrict__ S2_5h, const short* __restrict__ S2_6h,
                      const float* __restrict__ c5f, const float* __restrict__ c6f,
                      short* __restrict__ nodeC){
  int t = blockIdx.x*256 + threadIdx.x;
  if (t >= NNODES*320) return;
  int n = t / 320, ch = t - n*320;
  float out;
  if (ch < 128){
    float d5 = (float)(o5[n+1]-o5[n]), d6 = (float)(o6[n+1]-o6[n]);
    out = d5*bs2f(n5_5h[(size_t)n*128 + ch]) + d6*bs2f(n5_6h[(size_t)n*128 + ch]);
  } else if (ch < 256){
    int c = ch - 128;
    float s = 0.f;
    for (int i = o5[n]; i < o5[n+1]; ++i) s += bs2f(S2_5h[(size_t)(r5[i]/5)*128 + c]);
    for (int i = o6[n]; i < o6[n+1]; ++i) s += bs2f(S2_6h[(size_t)(r6[i]/6)*128 + c]);
    out = s;
  } else {
    int c = ch - 256;
    float s = 0.f;
    for (int i = o5[n]; i < o5[n+1]; ++i) s += c5f[(size_t)r5[i]*64 + c];
    for (int i = o6[n]; i < o6[n+1]; ++i) s += c6f[(size_t)r6[i]*64 + c];
    out = s;
  }
  nodeC[(size_t)n*320 + ch] = f2bs(out);
}

// fp32 -> bf16 stream convert, all 3 feature arrays in one launch
__global__ void f2h3_k(const float* __restrict__ e, const float* __restrict__ c5,
                       const float* __restrict__ c6, short* __restrict__ eh,
                       short* __restrict__ c5h, short* __restrict__ c6h){
  int t = blockIdx.x*256 + threadIdx.x;
  const float* s; short* d; int i;
  if (t < EROWS*16)                        { s=e;  d=eh;  i=t; }
  else if (t < EROWS*16 + C5ROWS*16)       { s=c5; d=c5h; i=t - EROWS*16; }
  else if (t < EROWS*16 + C5ROWS*16 + C6ROWS*16) { s=c6; d=c6h; i=t - EROWS*16 - C5ROWS*16; }
  else return;
  float4 v = ((const float4*)s)[i];
  short4 o; o.x=f2bs(v.x); o.y=f2bs(v.y); o.z=f2bs(v.z); o.w=f2bs(v.w);
  ((short4*)d)[i] = o;
}

// all 4 weight transposes, one launch. WT[n][k] = bf16(W[k][n])
__global__ void tr4_k(const float* __restrict__ eW1, const float* __restrict__ cW1,
                      const float* __restrict__ eW2, const float* __restrict__ cW2,
                      short* __restrict__ eW1T, short* __restrict__ cW1T,
                      short* __restrict__ eW2T, short* __restrict__ cW2T){
  int t = blockIdx.x*256 + threadIdx.x;
  if (t < 704*128){
    int k = t >> 7, n = t & 127; eW1T[(size_t)n*704 + k] = f2bs(eW1[t]);
  } else if (t < 704*128 + 320*128){
    int t2 = t - 704*128; int k = t2 >> 7, n = t2 & 127;
    cW1T[(size_t)n*320 + k] = f2bs(cW1[t2]);
  } else if (t < 704*128 + 320*128 + 128*64){
    int t3 = t - 704*128 - 320*128; int k = t3 >> 6, n = t3 & 63;
    eW2T[(size_t)n*128 + k] = f2bs(eW2[t3]);
  } else if (t < 704*128 + 320*128 + 2*128*64){
    int t4 = t - 704*128 - 320*128 - 128*64; int k = t4 >> 6, n = t4 & 63;
    cW2T[(size_t)n*128 + k] = f2bs(cW2[t4]);
  }
}

// final BatchNorm+ReLU on fp32 d_out (C=64), in place
__global__ void bnf_k(float* __restrict__ X, const float* __restrict__ ssum,
                      const float* __restrict__ ssq, const float* __restrict__ g,
                      const float* __restrict__ b, int M){
  int t = blockIdx.x*256 + threadIdx.x;
  if (t >= M*64) return;
  int ch = t & 63;
  float inv  = 1.f / (float)M;
  float mean = ssum[ch]*inv;
  float var  = fmaxf(ssq[ch]*inv - mean*mean, 0.f);
  float sc   = g[ch] * rsqrtf(var + 1e-5f);
  X[t] = fmaxf(sc*X[t] + (b[ch] - mean*sc), 0.f);
}

// ---------------- MFMA GEMM, barrier-free direct-B ----------------
// The per-iteration __syncthreads (hipcc drains vmcnt(0) before every
// s_barrier) defeated the B double-buffer pipeline -> LDS B-staging removed.
// B fragments load straight from L2-resident BT with a fully unrolled,
// BARRIER-FREE main loop (one barrier total, before the stats reduction).
// LOADER 1: edge rows  [ef_h(64) | nodeC_h[aS](320) | shfl-combined(320)], KC=704
// LOADER 2: cycle rows [n5h[aS](128) | S2h[m/RDIV](128) | featsh(64)],    KC=320
// LOADER 3: bf16 A + fused BN1 affine+ReLU computed inline from layer-1
//           stats (G0=ssum_in, G1=ssq_in as fp32; F0=gamma, F1=beta), KC=128
template<int LOADER, int NT, int OUTF32, int KC, int RDIV>
__global__ __launch_bounds__(256) void gemm_k(
    const short* __restrict__ A, const short* __restrict__ G0,
    const short* __restrict__ G1, const float* __restrict__ F0,
    const float* __restrict__ F1, const int* __restrict__ atoms,
    const short* __restrict__ BT, void* __restrict__ CoutV,
    float* __restrict__ ssum, float* __restrict__ ssq, int M)
{
  constexpr int NK = KC/32;          // k-slices
  constexpr int NC = NT*16;          // output cols
  __shared__ float sred[8*NC];       // [2 arrays][4 waves][NC]

  const int wv   = threadIdx.x >> 6;
  const int lane = threadIdx.x & 63;
  const int row0 = blockIdx.x*64 + wv*16;
  const int l15 = lane & 15, quad = lane >> 4;
  const bool act = (row0 < M);
  const int m = act ? (row0 + l15) : 0;

  int aS = 0, cyc = 0;
  if (LOADER == 1) aS = act ? atoms[m] : 0;
  if (LOADER == 2) { aS = act ? atoms[m] : 0; cyc = m / RDIV; }

  f32x4 acc[NT];
  #pragma unroll
  for (int nt = 0; nt < NT; ++nt) acc[nt] = (f32x4){0.f,0.f,0.f,0.f};

  if (act) {
    // ---- A prefetch: issue every gathered fragment load up front ----
    constexpr int NLD = (LOADER==1) ? 12 : (LOADER==2 ? 10 : NK);
    short8 af[NLD];
    #pragma unroll
    for (int kt = 0; kt < NLD; ++kt) {
      const int k0 = kt*32 + quad*8;
      if (LOADER == 1) {
        if (kt < 2) af[kt] = *reinterpret_cast<const short8*>(A + (size_t)m*64 + k0);
        else        af[kt] = *reinterpret_cast<const short8*>(G0 + (size_t)aS*320 + (k0-64));
      } else if (LOADER == 2) {
        if (kt < 4)      af[kt] = *reinterpret_cast<const short8*>(G0 + (size_t)aS*128 + k0);
        else if (kt < 8) af[kt] = *reinterpret_cast<const short8*>(G1 + (size_t)cyc*128 + (k0-128));
        else             af[kt] = *reinterpret_cast<const short8*>(A + (size_t)m*64 + (k0-256));
      } else {
        af[kt] = *reinterpret_cast<const short8*>(A + (size_t)m*KC + k0);
      }
    }

    const short* bp = BT + (size_t)l15*KC + quad*8;   // per-lane B base
    const float invM = 1.f / (float)M;

    #pragma unroll
    for (int kt = 0; kt < NK; ++kt) {
      const int k0 = kt*32 + quad*8;
      short8 afk;
      {
        short8 base = af[(kt < NLD) ? kt : (kt - 10)];
        if (LOADER == 3) {
          // inline BN1 affine from layer-1 stats (mkscale folded in)
          const float* ssin = reinterpret_cast<const float*>(G0);
          const float* qqin = reinterpret_cast<const float*>(G1);
          float ssv[8], qqv[8], gv[8], bv[8];
          *reinterpret_cast<float4*>(&ssv[0]) = *reinterpret_cast<const float4*>(ssin + k0);
          *reinterpret_cast<float4*>(&ssv[4]) = *reinterpret_cast<const float4*>(ssin + k0 + 4);
          *reinterpret_cast<float4*>(&qqv[0]) = *reinterpret_cast<const float4*>(qqin + k0);
          *reinterpret_cast<float4*>(&qqv[4]) = *reinterpret_cast<const float4*>(qqin + k0 + 4);
          *reinterpret_cast<float4*>(&gv[0])  = *reinterpret_cast<const float4*>(F0 + k0);
          *reinterpret_cast<float4*>(&gv[4])  = *reinterpret_cast<const float4*>(F0 + k0 + 4);
          *reinterpret_cast<float4*>(&bv[0])  = *reinterpret_cast<const float4*>(F1 + k0);
          *reinterpret_cast<float4*>(&bv[4])  = *reinterpret_cast<const float4*>(F1 + k0 + 4);
          #pragma unroll
          for (int j = 0; j < 8; ++j) {
            float mean = ssv[j]*invM;
            float var  = fmaxf(qqv[j]*invM - mean*mean, 0.f);
            float sc   = gv[j] * rsqrtf(var + 1e-5f);
            float sh   = bv[j] - mean*sc;
            afk[j] = f2bs(fmaxf(sc*bs2f(base[j]) + sh, 0.f));
          }
        } else if (LOADER == 1 && kt >= 12) {
          afk = combine_pair(base);
        } else {
          afk = base;
        }
      }
      #pragma unroll
      for (int nt = 0; nt < NT; ++nt) {
        const short8 bfg = *reinterpret_cast<const short8*>(bp + (size_t)nt*16*KC + kt*32);
        acc[nt] = __builtin_amdgcn_mfma_f32_16x16x32_bf16(afk, bfg, acc[nt], 0, 0, 0);
      }
    }
  }

  // ---- C write + per-block stats reduction (one barrier total) ----
  #pragma unroll
  for (int nt = 0; nt < NT; ++nt) {
    float ps = 0.f, pq = 0.f;
    if (act) {
      #pragma unroll
      for (int rg = 0; rg < 4; ++rg) {
        float v = acc[nt][rg];                     // D[row=quad*4+rg][col=l15]
        int r = row0 + quad*4 + rg;
        if (OUTF32) ((float*)CoutV)[(size_t)r*NC + nt*16 + l15] = v;
        else        ((short*)CoutV)[(size_t)r*NC + nt*16 + l15] = f2bs(v);
        ps += v; pq += v*v;
      }
    }
    ps += __shfl_xor(ps, 16); pq += __shfl_xor(pq, 16);
    ps += __shfl_xor(ps, 32); pq += __shfl_xor(pq, 32);
    if (lane < 16) {                               // quad == 0
      sred[wv*NC + nt*16 + lane]        = ps;
      sred[4*NC + wv*NC + nt*16 + lane] = pq;
    }
  }
  __syncthreads();
  for (int ch = threadIdx.x; ch < NC; ch += 256) {
    float s = sred[ch] + sred[NC + ch] + sred[2*NC + ch] + sred[3*NC + ch];
    float q = sred[4*NC + ch] + sred[5*NC + ch] + sred[6*NC + ch] + sred[7*NC + ch];
    atomicAdd(&ssum[ch], s);
    atomicAdd(&ssq[ch], q);
  }
}

static inline int cdiv(int a, int b){ return (a + b - 1)/b; }

extern "C" void kernel_launch(void* const* d_in, const int* in_sizes, int n_in,
                              void* d_out, int out_size, void* d_ws, size_t ws_size,
                              hipStream_t stream)
{
  const float* edge_feats = (const float*)d_in[0];
  const float* c5_feats   = (const float*)d_in[1];
  const float* c6_feats   = (const float*)d_in[2];
  const int*   e_atoms    = (const int*)d_in[3];
  const int*   c5_atoms   = (const int*)d_in[4];
  const int*   c6_atoms   = (const int*)d_in[5];
  const float* eW1 = (const float*)d_in[6];
  const float* eg1 = (const float*)d_in[7];
  const float* eb1 = (const float*)d_in[8];
  const float* eW2 = (const float*)d_in[9];
  const float* eg2 = (const float*)d_in[10];
  const float* eb2 = (const float*)d_in[11];
  const float* cW1 = (const float*)d_in[12];
  const float* cg1 = (const float*)d_in[13];
  const float* cb1 = (const float*)d_in[14];
  const float* cW2 = (const float*)d_in[15];
  const float* cg2 = (const float*)d_in[16];
  const float* cb2 = (const float*)d_in[17];
  float* out = (float*)d_out;
  (void)in_sizes; (void)n_in; (void)out_size; (void)ws_size;

  char* w = (char*)d_ws;
  auto alloc = [&](size_t bytes) -> char* {
    char* p = w; w += (bytes + 255) & ~(size_t)255; return p;
  };

  // ---- zero zone (~1 MB): histograms, cursors, stats ----
  char* zbase = w;
  int*  deg_e = (int*)alloc(NNODES*4);
  int*  deg_5 = (int*)alloc(NNODES*4);
  int*  deg_6 = (int*)alloc(NNODES*4);
  int*  cur_e = (int*)alloc(NNODES*4);
  int*  cur_5 = (int*)alloc(NNODES*4);
  int*  cur_6 = (int*)alloc(NNODES*4);
  float* stats = (float*)alloc(1152*4);
  size_t zbytes = (size_t)(w - zbase);

  float* se1 = stats;        float* qe1 = stats + 128;
  float* se2 = stats + 256;  float* qe2 = stats + 320;
  float* s51 = stats + 384;  float* q51 = stats + 512;
  float* s52 = stats + 640;  float* q52 = stats + 704;
  float* s61 = stats + 768;  float* q61 = stats + 896;
  float* s62 = stats + 1024; float* q62 = stats + 1088;

  // ---- write-before-read buffers ----
  int* offs_e = (int*)alloc((NNODES+1)*4);
  int* offs_5 = (int*)alloc((NNODES+1)*4);
  int* offs_6 = (int*)alloc((NNODES+1)*4);
  int* rows_e = (int*)alloc((size_t)EROWS*4);
  int* rows_5 = (int*)alloc((size_t)C5ROWS*4);
  int* rows_6 = (int*)alloc((size_t)C6ROWS*4);
  short* nodeC_h = (short*)alloc((size_t)NNODES*320*2);   // 25.6 MB
  short* n5_5h   = (short*)alloc((size_t)NNODES*128*2);   // 10.24 MB
  short* n5_6h   = (short*)alloc((size_t)NNODES*128*2);
  short* S2_5h   = (short*)alloc((size_t)NCYC5*128*2);    // 7.68 MB
  short* S2_6h   = (short*)alloc((size_t)NCYC6*128*2);    // 6.4 MB
  short* ef_h    = (short*)alloc((size_t)EROWS*64*2);     // 15.36 MB
  short* c5f_h   = (short*)alloc((size_t)C5ROWS*64*2);    // 19.2 MB
  short* c6f_h   = (short*)alloc((size_t)C6ROWS*64*2);    // 19.2 MB
  short* eW1T    = (short*)alloc((size_t)128*704*2);
  short* cW1T    = (short*)alloc((size_t)128*320*2);
  short* eW2T    = (short*)alloc((size_t)64*128*2);
  short* cW2T    = (short*)alloc((size_t)64*128*2);
  // h1 region (38.4 MB) shared by 3 MLPs; phase-1 fp32 temporaries alias it
  char*  h1reg = alloc((size_t)C5ROWS*128*2);
  short* h1    = (short*)h1reg;
  float* node_e = (float*)h1reg;                                          // 10.24 MB
  float* S1_5   = (float*)(h1reg + (size_t)NNODES*64*4);                  // 7.68 MB
  float* S1_6   = (float*)(h1reg + (size_t)NNODES*64*4 + (size_t)NCYC5*64*4); // 6.4 MB

  hipMemsetAsync(zbase, 0, zbytes, stream);

  // ---- CSR build (fused) ----
  const int TOTROWS = EROWS + C5ROWS + C6ROWS;
  hist3_k<<<cdiv(TOTROWS,256),256,0,stream>>>(e_atoms, c5_atoms, c6_atoms,
                                              deg_e, deg_5, deg_6);
  scan3_k<<<3,1024,0,stream>>>(deg_e, deg_5, deg_6, offs_e, offs_5, offs_6);
  fill3_k<<<cdiv(TOTROWS,256),256,0,stream>>>(e_atoms, c5_atoms, c6_atoms,
                                              offs_e, offs_5, offs_6,
                                              cur_e, cur_5, cur_6,
                                              rows_e, rows_5, rows_6);

  // ---- bf16 copies + weight transposes (fused) ----
  f2h3_k<<<cdiv((EROWS+C5ROWS+C6ROWS)*16,256),256,0,stream>>>(
      edge_feats, c5_feats, c6_feats, ef_h, c5f_h, c6f_h);
  tr4_k<<<cdiv(704*128 + 320*128 + 2*128*64,256),256,0,stream>>>(
      eW1, cW1, eW2, cW2, eW1T, cW1T, eW2T, cW2T);

  // ---- phase 1: node/cycle aggregates (fused, no RMW) ----
  gne_k<<<cdiv(NNODES*64,256),256,0,stream>>>(edge_feats, offs_e, rows_e, node_e);
  s1f_k<<<cdiv(NCYC5*64 + NCYC6*64,256),256,0,stream>>>(node_e, c5_atoms, c6_atoms,
                                                        S1_5, S1_6);
  n5f_k<<<cdiv(NNODES*64,256),256,0,stream>>>(node_e, offs_5, rows_5, offs_6, rows_6,
                                              S1_5, S1_6, n5_5h, n5_6h);
  s2f_k<<<cdiv(NCYC5*128 + NCYC6*128,256),256,0,stream>>>(n5_5h, n5_6h,
                                                          c5_atoms, c6_atoms,
                                                          S2_5h, S2_6h);
  ncf_k<<<cdiv(NNODES*320,256),256,0,stream>>>(n5_5h, n5_6h, offs_5, rows_5,
                                               offs_6, rows_6, S2_5h, S2_6h,
                                               c5_feats, c6_feats, nodeC_h);

  float* out_e = out;
  float* out_5 = out + (size_t)EROWS*64;
  float* out_6 = out + (size_t)(EROWS + C5ROWS)*64;

  // ---- edge MLP ----
  gemm_k<1,8,0,704,1><<<cdiv(EROWS,64),256,0,stream>>>(ef_h, nodeC_h, nullptr, nullptr, nullptr,
                                                       e_atoms, eW1T, h1, se1, qe1, EROWS);
  gemm_k<3,4,1,128,1><<<cdiv(EROWS,64),256,0,stream>>>(h1, (const short*)se1, (const short*)qe1,
                                                       eg1, eb1, nullptr, eW2T, out_e,
                                                       se2, qe2, EROWS);
  bnf_k<<<cdiv(EROWS*64,256),256,0,stream>>>(out_e, se2, qe2, eg2, eb2, EROWS);

  // ---- cycle5 MLP ----
  gemm_k<2,8,0,320,5><<<cdiv(C5ROWS,64),256,0,stream>>>(c5f_h, n5_5h, S2_5h, nullptr, nullptr,
                                                        c5_atoms, cW1T, h1, s51, q51, C5ROWS);
  gemm_k<3,4,1,128,1><<<cdiv(C5ROWS,64),256,0,stream>>>(h1, (const short*)s51, (const short*)q51,
                                                        cg1, cb1, nullptr, cW2T, out_5,
                                                        s52, q52, C5ROWS);
  bnf_k<<<cdiv(C5ROWS*64,256),256,0,stream>>>(out_5, s52, q52, cg2, cb2, C5ROWS);

  // ---- cycle6 MLP ----
  gemm_k<2,8,0,320,6><<<cdiv(C6ROWS,64),256,0,stream>>>(c6f_h, n5_6h, S2_6h, nullptr, nullptr,
                                                        c6_atoms, cW1T, h1, s61, q61, C6ROWS);
  gemm_k<3,4,1,128,1><<<cdiv(C6ROWS,64),256,0,stream>>>(h1, (const short*)s61, (const short*)q61,
                                                        cg1, cb1, nullptr, cW2T, out_6,
                                                        s62, q62, C6ROWS);
  bnf_k<<<cdiv(C6ROWS*64,256),256,0,stream>>>(out_6, s62, q62, cg2, cb2, C6ROWS);
}

// Round 5
// 978.494 us; speedup vs baseline: 1.1861x; 1.1861x over previous
//
#include <hip/hip_runtime.h>
#include <hip/hip_bf16.h>

#define NNODES 40000
#define NEDGE  60000
#define NCYC5  30000
#define NCYC6  25000
#define EROWS  (2*NEDGE)    // 120000
#define C5ROWS (5*NCYC5)    // 150000
#define C6ROWS (6*NCYC6)    // 150000

typedef __attribute__((ext_vector_type(8))) short short8;   // 8 bf16 lanes
typedef __attribute__((ext_vector_type(4))) float f32x4;

__device__ __forceinline__ short f2bs(float x){
  union { __hip_bfloat16 h; short s; } u; u.h = __float2bfloat16(x); return u.s;
}
__device__ __forceinline__ float bs2f(short s){
  union { short s; __hip_bfloat16 h; } u; u.s = s; return __bfloat162float(u.h);
}

// rows m and m^1 live in adjacent lanes (l15 pairs): piece3 = val(m)+val(m^1)
__device__ __forceinline__ short8 combine_pair(short8 a){
  union U { short8 v; int i[4]; } u, w;
  u.v = a;
  #pragma unroll
  for (int j = 0; j < 4; ++j) w.i[j] = __shfl_xor(u.i[j], 1);
  short8 r;
  #pragma unroll
  for (int j = 0; j < 8; ++j) r[j] = f2bs(bs2f(a[j]) + bs2f(w.v[j]));
  return r;
}

// drain-free barrier: LDS ops must land (lgkmcnt) but global prefetches
// stay IN FLIGHT across the barrier (unlike __syncthreads' vmcnt(0) drain)
__device__ __forceinline__ void lds_barrier(){
  asm volatile("s_waitcnt lgkmcnt(0)" ::: "memory");
  __builtin_amdgcn_s_barrier();
}

// ---------------- CSR build (fused 3-range) ----------------
__global__ void hist3_k(const int* __restrict__ ea, const int* __restrict__ c5a,
                        const int* __restrict__ c6a, int* __restrict__ de,
                        int* __restrict__ d5, int* __restrict__ d6){
  int r = blockIdx.x*256 + threadIdx.x;
  if (r < EROWS)                        atomicAdd(&de[ea[r]], 1);
  else if (r < EROWS + C5ROWS)          atomicAdd(&d5[c5a[r - EROWS]], 1);
  else if (r < EROWS + C5ROWS + C6ROWS) atomicAdd(&d6[c6a[r - EROWS - C5ROWS]], 1);
}

// 3 blocks, 1024 threads each: exclusive scan of one deg array per block
__global__ void scan3_k(const int* __restrict__ d0, const int* __restrict__ d1,
                        const int* __restrict__ d2, int* __restrict__ o0,
                        int* __restrict__ o1, int* __restrict__ o2){
  const int* deg = blockIdx.x==0 ? d0 : (blockIdx.x==1 ? d1 : d2);
  int* offs      = blockIdx.x==0 ? o0 : (blockIdx.x==1 ? o1 : o2);
  const int N = NNODES;
  __shared__ int part[1024];
  int tid = threadIdx.x;
  const int chunk = (N + 1023) / 1024;
  int lo = tid*chunk, hi = min(lo+chunk, N);
  int s = 0;
  for (int i = lo; i < hi; ++i) s += deg[i];
  part[tid] = s;
  __syncthreads();
  for (int d = 1; d < 1024; d <<= 1){
    int v = (tid >= d) ? part[tid-d] : 0;
    __syncthreads();
    part[tid] += v;
    __syncthreads();
  }
  int pref = (tid == 0) ? 0 : part[tid-1];
  for (int i = lo; i < hi; ++i){ offs[i] = pref; pref += deg[i]; }
  if (tid == 1023) offs[N] = part[1023];
}

__global__ void fill3_k(const int* __restrict__ ea, const int* __restrict__ c5a,
                        const int* __restrict__ c6a,
                        const int* __restrict__ oe, const int* __restrict__ o5,
                        const int* __restrict__ o6,
                        int* __restrict__ cue, int* __restrict__ cu5,
                        int* __restrict__ cu6,
                        int* __restrict__ re, int* __restrict__ r5,
                        int* __restrict__ r6){
  int r = blockIdx.x*256 + threadIdx.x;
  if (r < EROWS){
    int a = ea[r]; re[oe[a] + atomicAdd(&cue[a],1)] = r;
  } else if (r < EROWS + C5ROWS){
    int rr = r - EROWS; int a = c5a[rr]; r5[o5[a] + atomicAdd(&cu5[a],1)] = rr;
  } else if (r < EROWS + C5ROWS + C6ROWS){
    int rr = r - EROWS - C5ROWS; int a = c6a[rr]; r6[o6[a] + atomicAdd(&cu6[a],1)] = rr;
  }
}

// ---------------- fused phase-1 kernels ----------------
__global__ void gne_k(const float* __restrict__ ef, const int* __restrict__ offs,
                      const int* __restrict__ rows, float* __restrict__ node_e){
  int t = blockIdx.x*256 + threadIdx.x;
  if (t >= NNODES*64) return;
  int n = t >> 6, ch = t & 63;
  int o = offs[n], e = offs[n+1];
  float s = 0.f;
  for (int i = o; i < e; ++i) s += ef[(size_t)rows[i]*64 + ch];
  node_e[t] = s;
}

__global__ void s1f_k(const float* __restrict__ node_e,
                      const int* __restrict__ a5, const int* __restrict__ a6,
                      float* __restrict__ S1_5, float* __restrict__ S1_6){
  int t = blockIdx.x*256 + threadIdx.x;
  if (t < NCYC5*64){
    int c = t >> 6, ch = t & 63;
    const int* ap = a5 + c*5;
    float s = 0.f;
    #pragma unroll
    for (int j = 0; j < 5; ++j) s += node_e[(size_t)ap[j]*64 + ch];
    S1_5[t] = s;
  } else if (t < NCYC5*64 + NCYC6*64){
    int t2 = t - NCYC5*64;
    int c = t2 >> 6, ch = t2 & 63;
    const int* ap = a6 + c*6;
    float s = 0.f;
    #pragma unroll
    for (int j = 0; j < 6; ++j) s += node_e[(size_t)ap[j]*64 + ch];
    S1_6[t2] = s;
  }
}

__global__ void n5f_k(const float* __restrict__ node_e,
                      const int* __restrict__ o5, const int* __restrict__ r5,
                      const int* __restrict__ o6, const int* __restrict__ r6,
                      const float* __restrict__ S1_5, const float* __restrict__ S1_6,
                      short* __restrict__ n5_5h, short* __restrict__ n5_6h){
  int t = blockIdx.x*256 + threadIdx.x;
  if (t >= NNODES*64) return;
  int n = t >> 6, ch = t & 63;
  float v = node_e[t];
  int a5 = o5[n], b5 = o5[n+1], a6 = o6[n], b6 = o6[n+1];
  float s5 = 0.f, s6 = 0.f;
  for (int i = a5; i < b5; ++i) s5 += S1_5[(size_t)(r5[i]/5)*64 + ch];
  for (int i = a6; i < b6; ++i) s6 += S1_6[(size_t)(r6[i]/6)*64 + ch];
  n5_5h[(size_t)n*128 + ch]      = f2bs((float)(b5-a5) * v);
  n5_5h[(size_t)n*128 + 64 + ch] = f2bs(s5);
  n5_6h[(size_t)n*128 + ch]      = f2bs((float)(b6-a6) * v);
  n5_6h[(size_t)n*128 + 64 + ch] = f2bs(s6);
}

__global__ void s2f_k(const short* __restrict__ n5_5h, const short* __restrict__ n5_6h,
                      const int* __restrict__ a5, const int* __restrict__ a6,
                      short* __restrict__ S2_5h, short* __restrict__ S2_6h){
  int t = blockIdx.x*256 + threadIdx.x;
  if (t < NCYC5*128){
    int c = t >> 7, ch = t & 127;
    const int* ap = a5 + c*5;
    float s = 0.f;
    #pragma unroll
    for (int j = 0; j < 5; ++j) s += bs2f(n5_5h[(size_t)ap[j]*128 + ch]);
    S2_5h[t] = f2bs(s);
  } else if (t < NCYC5*128 + NCYC6*128){
    int t2 = t - NCYC5*128;
    int c = t2 >> 7, ch = t2 & 127;
    const int* ap = a6 + c*6;
    float s = 0.f;
    #pragma unroll
    for (int j = 0; j < 6; ++j) s += bs2f(n5_6h[(size_t)ap[j]*128 + ch]);
    S2_6h[t2] = f2bs(s);
  }
}

__global__ void ncf_k(const short* __restrict__ n5_5h, const short* __restrict__ n5_6h,
                      const int* __restrict__ o5, const int* __restrict__ r5,
                      const int* __restrict__ o6, const int* __restrict__ r6,
                      const short* __restrict__ S2_5h, const short* __restrict__ S2_6h,
                      const float* __restrict__ c5f, const float* __restrict__ c6f,
                      short* __restrict__ nodeC){
  int t = blockIdx.x*256 + threadIdx.x;
  if (t >= NNODES*320) return;
  int n = t / 320, ch = t - n*320;
  float out;
  if (ch < 128){
    float d5 = (float)(o5[n+1]-o5[n]), d6 = (float)(o6[n+1]-o6[n]);
    out = d5*bs2f(n5_5h[(size_t)n*128 + ch]) + d6*bs2f(n5_6h[(size_t)n*128 + ch]);
  } else if (ch < 256){
    int c = ch - 128;
    float s = 0.f;
    for (int i = o5[n]; i < o5[n+1]; ++i) s += bs2f(S2_5h[(size_t)(r5[i]/5)*128 + c]);
    for (int i = o6[n]; i < o6[n+1]; ++i) s += bs2f(S2_6h[(size_t)(r6[i]/6)*128 + c]);
    out = s;
  } else {
    int c = ch - 256;
    float s = 0.f;
    for (int i = o5[n]; i < o5[n+1]; ++i) s += c5f[(size_t)r5[i]*64 + c];
    for (int i = o6[n]; i < o6[n+1]; ++i) s += c6f[(size_t)r6[i]*64 + c];
    out = s;
  }
  nodeC[(size_t)n*320 + ch] = f2bs(out);
}

__global__ void f2h3_k(const float* __restrict__ e, const float* __restrict__ c5,
                       const float* __restrict__ c6, short* __restrict__ eh,
                       short* __restrict__ c5h, short* __restrict__ c6h){
  int t = blockIdx.x*256 + threadIdx.x;
  const float* s; short* d; int i;
  if (t < EROWS*16)                        { s=e;  d=eh;  i=t; }
  else if (t < EROWS*16 + C5ROWS*16)       { s=c5; d=c5h; i=t - EROWS*16; }
  else if (t < EROWS*16 + C5ROWS*16 + C6ROWS*16) { s=c6; d=c6h; i=t - EROWS*16 - C5ROWS*16; }
  else return;
  float4 v = ((const float4*)s)[i];
  short4 o; o.x=f2bs(v.x); o.y=f2bs(v.y); o.z=f2bs(v.z); o.w=f2bs(v.w);
  ((short4*)d)[i] = o;
}

__global__ void tr4_k(const float* __restrict__ eW1, const float* __restrict__ cW1,
                      const float* __restrict__ eW2, const float* __restrict__ cW2,
                      short* __restrict__ eW1T, short* __restrict__ cW1T,
                      short* __restrict__ eW2T, short* __restrict__ cW2T){
  int t = blockIdx.x*256 + threadIdx.x;
  if (t < 704*128){
    int k = t >> 7, n = t & 127; eW1T[(size_t)n*704 + k] = f2bs(eW1[t]);
  } else if (t < 704*128 + 320*128){
    int t2 = t - 704*128; int k = t2 >> 7, n = t2 & 127;
    cW1T[(size_t)n*320 + k] = f2bs(cW1[t2]);
  } else if (t < 704*128 + 320*128 + 128*64){
    int t3 = t - 704*128 - 320*128; int k = t3 >> 6, n = t3 & 63;
    eW2T[(size_t)n*128 + k] = f2bs(eW2[t3]);
  } else if (t < 704*128 + 320*128 + 2*128*64){
    int t4 = t - 704*128 - 320*128 - 128*64; int k = t4 >> 6, n = t4 & 63;
    cW2T[(size_t)n*128 + k] = f2bs(cW2[t4]);
  }
}

// final BatchNorm+ReLU on fp32 d_out (C=64), in place
__global__ void bnf_k(float* __restrict__ X, const float* __restrict__ ssum,
                      const float* __restrict__ ssq, const float* __restrict__ g,
                      const float* __restrict__ b, int M){
  int t = blockIdx.x*256 + threadIdx.x;
  if (t >= M*64) return;
  int ch = t & 63;
  float inv  = 1.f / (float)M;
  float mean = ssum[ch]*inv;
  float var  = fmaxf(ssq[ch]*inv - mean*mean, 0.f);
  float sc   = g[ch] * rsqrtf(var + 1e-5f);
  X[t] = fmaxf(sc*X[t] + (b[ch] - mean*sc), 0.f);
}

// ---------------- MFMA GEMM: LDS B-staging + drain-free barriers ----------------
// Round-5: round-2's LDS staging structure (78us, 2.3x better than direct-B)
// with __syncthreads replaced by lds_barrier() (lgkmcnt(0) + raw s_barrier).
// hipcc's __syncthreads emits s_waitcnt vmcnt(0) which collapsed the depth-2
// global prefetch pipeline at every iteration; raw s_barrier keeps the
// kt+1/kt+2 slice loads in flight across the barrier (T3/T4 pattern).
// Correctness: writes/reads alternate LDS buffers; lgkmcnt(0) in every wave
// before each barrier orders ds_write (publish) and drains this wave's
// ds_reads of the buffer about to be overwritten two iterations later.
// LOADER 1: edge rows  [ef_h(64) | nodeC_h[aS](320) | shfl-combined(320)], KC=704
// LOADER 2: cycle rows [n5h[aS](128) | S2h[m/RDIV](128) | featsh(64)],    KC=320
// LOADER 3: bf16 A + inline BN1 affine+ReLU from layer-1 stats
//           (G0=ssum_in fp32, G1=ssq_in fp32, F0=gamma, F1=beta), KC=128
template<int LOADER, int NT, int OUTF32, int KC, int RDIV>
__global__ __launch_bounds__(256) void gemm_k(
    const short* __restrict__ A, const short* __restrict__ G0,
    const short* __restrict__ G1, const float* __restrict__ F0,
    const float* __restrict__ F1, const int* __restrict__ atoms,
    const short* __restrict__ BT, void* __restrict__ CoutV,
    float* __restrict__ ssum, float* __restrict__ ssq, int M)
{
  constexpr int NK = KC/32;          // k-slices
  static_assert(NK % 2 == 0, "final MFMA must read LDS buffer 1 (sred aliases buffer 0)");
  constexpr int NC = NT*16;          // output cols = BT rows staged
  constexpr int CH = (NC*4)/256;     // 16B chunks per thread per slice
  __shared__ short lds[2*NC*32];     // 2 slice buffers

  const int wv   = threadIdx.x >> 6;
  const int lane = threadIdx.x & 63;
  const int row0 = blockIdx.x*64 + wv*16;
  const int l15 = lane & 15, quad = lane >> 4;
  // out-of-range waves still participate in staging + barriers
  const bool act = (row0 < M);
  const int m = act ? (row0 + l15) : 0;

  int aS = 0, cyc = 0;
  if (LOADER == 1) aS = act ? atoms[m] : 0;
  if (LOADER == 2) { aS = act ? atoms[m] : 0; cyc = m / RDIV; }

  // ---- A prefetch: issue every gathered fragment load up front ----
  constexpr int NLD = (LOADER==1) ? 12 : (LOADER==2 ? 10 : NK);
  short8 af[NLD];
  if (act) {
    #pragma unroll
    for (int kt = 0; kt < NLD; ++kt) {
      const int k0 = kt*32 + quad*8;
      if (LOADER == 1) {
        if (kt < 2) af[kt] = *reinterpret_cast<const short8*>(A + (size_t)m*64 + k0);
        else        af[kt] = *reinterpret_cast<const short8*>(G0 + (size_t)aS*320 + (k0-64));
      } else if (LOADER == 2) {
        if (kt < 4)      af[kt] = *reinterpret_cast<const short8*>(G0 + (size_t)aS*128 + k0);
        else if (kt < 8) af[kt] = *reinterpret_cast<const short8*>(G1 + (size_t)cyc*128 + (k0-128));
        else             af[kt] = *reinterpret_cast<const short8*>(A + (size_t)m*64 + (k0-256));
      } else {
        af[kt] = *reinterpret_cast<const short8*>(A + (size_t)m*KC + k0);
      }
    }
  }

  // ---- B slice staging helpers (all 256 threads) ----
  auto stage_load = [&](int kt, short8* r){
    #pragma unroll
    for (int i = 0; i < CH; ++i) {
      int id = i*256 + (int)threadIdx.x;        // chunk id: n = id>>2, c = id&3
      r[i] = *reinterpret_cast<const short8*>(BT + (size_t)(id>>2)*KC + kt*32 + (id&3)*8);
    }
  };
  auto stage_write = [&](int b, short8* r){
    #pragma unroll
    for (int i = 0; i < CH; ++i) {
      int id = i*256 + (int)threadIdx.x;
      int n = id>>2, c = id&3;
      *reinterpret_cast<short8*>(&lds[b*NC*32 + n*32 + ((c ^ ((n>>1)&3)))*8]) = r[i];
    }
  };

  f32x4 acc[NT];
  #pragma unroll
  for (int nt = 0; nt < NT; ++nt) acc[nt] = (f32x4){0.f,0.f,0.f,0.f};

  // depth-2 pipeline: slices kt and kt+1 in flight in registers
  short8 sr0[CH], sr1[CH], sr2[CH];
  stage_load(0, sr0);
  if (NK > 1) stage_load(1, sr1);

  const float invM = 1.f / (float)M;

  #pragma unroll
  for (int kt = 0; kt < NK; ++kt) {
    short8* cur = (kt % 3 == 0) ? sr0 : ((kt % 3 == 1) ? sr1 : sr2);
    stage_write(kt & 1, cur);                 // compiler waits vmcnt for cur only
    if (kt + 2 < NK) {
      short8* nxt = ((kt+2) % 3 == 0) ? sr0 : (((kt+2) % 3 == 1) ? sr1 : sr2);
      stage_load(kt + 2, nxt);                // stays in flight across barrier
    }
    lds_barrier();

    if (act) {
      const int k0 = kt*32 + quad*8;
      short8 afk;
      {
        short8 base = af[(kt < NLD) ? kt : (kt - 10)];
        if (LOADER == 3) {
          const float* ssin = reinterpret_cast<const float*>(G0);
          const float* qqin = reinterpret_cast<const float*>(G1);
          float ssv[8], qqv[8], gv[8], bv[8];
          *reinterpret_cast<float4*>(&ssv[0]) = *reinterpret_cast<const float4*>(ssin + k0);
          *reinterpret_cast<float4*>(&ssv[4]) = *reinterpret_cast<const float4*>(ssin + k0 + 4);
          *reinterpret_cast<float4*>(&qqv[0]) = *reinterpret_cast<const float4*>(qqin + k0);
          *reinterpret_cast<float4*>(&qqv[4]) = *reinterpret_cast<const float4*>(qqin + k0 + 4);
          *reinterpret_cast<float4*>(&gv[0])  = *reinterpret_cast<const float4*>(F0 + k0);
          *reinterpret_cast<float4*>(&gv[4])  = *reinterpret_cast<const float4*>(F0 + k0 + 4);
          *reinterpret_cast<float4*>(&bv[0])  = *reinterpret_cast<const float4*>(F1 + k0);
          *reinterpret_cast<float4*>(&bv[4])  = *reinterpret_cast<const float4*>(F1 + k0 + 4);
          #pragma unroll
          for (int j = 0; j < 8; ++j) {
            float mean = ssv[j]*invM;
            float var  = fmaxf(qqv[j]*invM - mean*mean, 0.f);
            float sc   = gv[j] * rsqrtf(var + 1e-5f);
            float sh   = bv[j] - mean*sc;
            afk[j] = f2bs(fmaxf(sc*bs2f(base[j]) + sh, 0.f));
          }
        } else if (LOADER == 1 && kt >= 12) {
          afk = combine_pair(base);
        } else {
          afk = base;
        }
      }
      #pragma unroll
      for (int nt = 0; nt < NT; ++nt) {
        const int n = nt*16 + l15;
        const short8 bfg = *reinterpret_cast<const short8*>(
            &lds[(kt&1)*NC*32 + n*32 + ((quad ^ ((n>>1)&3)))*8]);
        acc[nt] = __builtin_amdgcn_mfma_f32_16x16x32_bf16(afk, bfg, acc[nt], 0, 0, 0);
      }
    }
  }

  // ---- C write + per-block stats reduction ----
  // sred aliases LDS slice-buffer 0; final kt (= NK-1, odd) read buffer 1.
  float* sred = reinterpret_cast<float*>(lds);

  #pragma unroll
  for (int nt = 0; nt < NT; ++nt) {
    float ps = 0.f, pq = 0.f;
    if (act) {
      #pragma unroll
      for (int rg = 0; rg < 4; ++rg) {
        float v = acc[nt][rg];                     // D[row=quad*4+rg][col=l15]
        int r = row0 + quad*4 + rg;
        if (OUTF32) ((float*)CoutV)[(size_t)r*NC + nt*16 + l15] = v;
        else        ((short*)CoutV)[(size_t)r*NC + nt*16 + l15] = f2bs(v);
        ps += v; pq += v*v;
      }
    }
    ps += __shfl_xor(ps, 16); pq += __shfl_xor(pq, 16);
    ps += __shfl_xor(ps, 32); pq += __shfl_xor(pq, 32);
    if (lane < 16) {                               // quad == 0
      sred[wv*NC + nt*16 + lane]        = ps;
      sred[4*NC + wv*NC + nt*16 + lane] = pq;
    }
  }
  __syncthreads();
  for (int ch = threadIdx.x; ch < NC; ch += 256) {
    float s = sred[ch] + sred[NC + ch] + sred[2*NC + ch] + sred[3*NC + ch];
    float q = sred[4*NC + ch] + sred[5*NC + ch] + sred[6*NC + ch] + sred[7*NC + ch];
    atomicAdd(&ssum[ch], s);
    atomicAdd(&ssq[ch], q);
  }
}

static inline int cdiv(int a, int b){ return (a + b - 1)/b; }

extern "C" void kernel_launch(void* const* d_in, const int* in_sizes, int n_in,
                              void* d_out, int out_size, void* d_ws, size_t ws_size,
                              hipStream_t stream)
{
  const float* edge_feats = (const float*)d_in[0];
  const float* c5_feats   = (const float*)d_in[1];
  const float* c6_feats   = (const float*)d_in[2];
  const int*   e_atoms    = (const int*)d_in[3];
  const int*   c5_atoms   = (const int*)d_in[4];
  const int*   c6_atoms   = (const int*)d_in[5];
  const float* eW1 = (const float*)d_in[6];
  const float* eg1 = (const float*)d_in[7];
  const float* eb1 = (const float*)d_in[8];
  const float* eW2 = (const float*)d_in[9];
  const float* eg2 = (const float*)d_in[10];
  const float* eb2 = (const float*)d_in[11];
  const float* cW1 = (const float*)d_in[12];
  const float* cg1 = (const float*)d_in[13];
  const float* cb1 = (const float*)d_in[14];
  const float* cW2 = (const float*)d_in[15];
  const float* cg2 = (const float*)d_in[16];
  const float* cb2 = (const float*)d_in[17];
  float* out = (float*)d_out;
  (void)in_sizes; (void)n_in; (void)out_size; (void)ws_size;

  char* w = (char*)d_ws;
  auto alloc = [&](size_t bytes) -> char* {
    char* p = w; w += (bytes + 255) & ~(size_t)255; return p;
  };

  // ---- zero zone (~1 MB): histograms, cursors, stats ----
  char* zbase = w;
  int*  deg_e = (int*)alloc(NNODES*4);
  int*  deg_5 = (int*)alloc(NNODES*4);
  int*  deg_6 = (int*)alloc(NNODES*4);
  int*  cur_e = (int*)alloc(NNODES*4);
  int*  cur_5 = (int*)alloc(NNODES*4);
  int*  cur_6 = (int*)alloc(NNODES*4);
  float* stats = (float*)alloc(1152*4);
  size_t zbytes = (size_t)(w - zbase);

  float* se1 = stats;        float* qe1 = stats + 128;
  float* se2 = stats + 256;  float* qe2 = stats + 320;
  float* s51 = stats + 384;  float* q51 = stats + 512;
  float* s52 = stats + 640;  float* q52 = stats + 704;
  float* s61 = stats + 768;  float* q61 = stats + 896;
  float* s62 = stats + 1024; float* q62 = stats + 1088;

  // ---- write-before-read buffers ----
  int* offs_e = (int*)alloc((NNODES+1)*4);
  int* offs_5 = (int*)alloc((NNODES+1)*4);
  int* offs_6 = (int*)alloc((NNODES+1)*4);
  int* rows_e = (int*)alloc((size_t)EROWS*4);
  int* rows_5 = (int*)alloc((size_t)C5ROWS*4);
  int* rows_6 = (int*)alloc((size_t)C6ROWS*4);
  short* nodeC_h = (short*)alloc((size_t)NNODES*320*2);   // 25.6 MB
  short* n5_5h   = (short*)alloc((size_t)NNODES*128*2);   // 10.24 MB
  short* n5_6h   = (short*)alloc((size_t)NNODES*128*2);
  short* S2_5h   = (short*)alloc((size_t)NCYC5*128*2);    // 7.68 MB
  short* S2_6h   = (short*)alloc((size_t)NCYC6*128*2);    // 6.4 MB
  short* ef_h    = (short*)alloc((size_t)EROWS*64*2);     // 15.36 MB
  short* c5f_h   = (short*)alloc((size_t)C5ROWS*64*2);    // 19.2 MB
  short* c6f_h   = (short*)alloc((size_t)C6ROWS*64*2);    // 19.2 MB
  short* eW1T    = (short*)alloc((size_t)128*704*2);
  short* cW1T    = (short*)alloc((size_t)128*320*2);
  short* eW2T    = (short*)alloc((size_t)64*128*2);
  short* cW2T    = (short*)alloc((size_t)64*128*2);
  // h1 region (38.4 MB) shared by 3 MLPs; phase-1 fp32 temporaries alias it
  char*  h1reg = alloc((size_t)C5ROWS*128*2);
  short* h1    = (short*)h1reg;
  float* node_e = (float*)h1reg;                                          // 10.24 MB
  float* S1_5   = (float*)(h1reg + (size_t)NNODES*64*4);                  // 7.68 MB
  float* S1_6   = (float*)(h1reg + (size_t)NNODES*64*4 + (size_t)NCYC5*64*4); // 6.4 MB

  hipMemsetAsync(zbase, 0, zbytes, stream);

  // ---- CSR build (fused) ----
  const int TOTROWS = EROWS + C5ROWS + C6ROWS;
  hist3_k<<<cdiv(TOTROWS,256),256,0,stream>>>(e_atoms, c5_atoms, c6_atoms,
                                              deg_e, deg_5, deg_6);
  scan3_k<<<3,1024,0,stream>>>(deg_e, deg_5, deg_6, offs_e, offs_5, offs_6);
  fill3_k<<<cdiv(TOTROWS,256),256,0,stream>>>(e_atoms, c5_atoms, c6_atoms,
                                              offs_e, offs_5, offs_6,
                                              cur_e, cur_5, cur_6,
                                              rows_e, rows_5, rows_6);

  // ---- bf16 copies + weight transposes (fused) ----
  f2h3_k<<<cdiv((EROWS+C5ROWS+C6ROWS)*16,256),256,0,stream>>>(
      edge_feats, c5_feats, c6_feats, ef_h, c5f_h, c6f_h);
  tr4_k<<<cdiv(704*128 + 320*128 + 2*128*64,256),256,0,stream>>>(
      eW1, cW1, eW2, cW2, eW1T, cW1T, eW2T, cW2T);

  // ---- phase 1: node/cycle aggregates (fused, no RMW) ----
  gne_k<<<cdiv(NNODES*64,256),256,0,stream>>>(edge_feats, offs_e, rows_e, node_e);
  s1f_k<<<cdiv(NCYC5*64 + NCYC6*64,256),256,0,stream>>>(node_e, c5_atoms, c6_atoms,
                                                        S1_5, S1_6);
  n5f_k<<<cdiv(NNODES*64,256),256,0,stream>>>(node_e, offs_5, rows_5, offs_6, rows_6,
                                              S1_5, S1_6, n5_5h, n5_6h);
  s2f_k<<<cdiv(NCYC5*128 + NCYC6*128,256),256,0,stream>>>(n5_5h, n5_6h,
                                                          c5_atoms, c6_atoms,
                                                          S2_5h, S2_6h);
  ncf_k<<<cdiv(NNODES*320,256),256,0,stream>>>(n5_5h, n5_6h, offs_5, rows_5,
                                               offs_6, rows_6, S2_5h, S2_6h,
                                               c5_feats, c6_feats, nodeC_h);

  float* out_e = out;
  float* out_5 = out + (size_t)EROWS*64;
  float* out_6 = out + (size_t)(EROWS + C5ROWS)*64;

  // ---- edge MLP ----
  gemm_k<1,8,0,704,1><<<cdiv(EROWS,64),256,0,stream>>>(ef_h, nodeC_h, nullptr, nullptr, nullptr,
                                                       e_atoms, eW1T, h1, se1, qe1, EROWS);
  gemm_k<3,4,1,128,1><<<cdiv(EROWS,64),256,0,stream>>>(h1, (const short*)se1, (const short*)qe1,
                                                       eg1, eb1, nullptr, eW2T, out_e,
                                                       se2, qe2, EROWS);
  bnf_k<<<cdiv(EROWS*64,256),256,0,stream>>>(out_e, se2, qe2, eg2, eb2, EROWS);

  // ---- cycle5 MLP ----
  gemm_k<2,8,0,320,5><<<cdiv(C5ROWS,64),256,0,stream>>>(c5f_h, n5_5h, S2_5h, nullptr, nullptr,
                                                        c5_atoms, cW1T, h1, s51, q51, C5ROWS);
  gemm_k<3,4,1,128,1><<<cdiv(C5ROWS,64),256,0,stream>>>(h1, (const short*)s51, (const short*)q51,
                                                        cg1, cb1, nullptr, cW2T, out_5,
                                                        s52, q52, C5ROWS);
  bnf_k<<<cdiv(C5ROWS*64,256),256,0,stream>>>(out_5, s52, q52, cg2, cb2, C5ROWS);

  // ---- cycle6 MLP ----
  gemm_k<2,8,0,320,6><<<cdiv(C6ROWS,64),256,0,stream>>>(c6f_h, n5_6h, S2_6h, nullptr, nullptr,
                                                        c6_atoms, cW1T, h1, s61, q61, C6ROWS);
  gemm_k<3,4,1,128,1><<<cdiv(C6ROWS,64),256,0,stream>>>(h1, (const short*)s61, (const short*)q61,
                                                        cg1, cb1, nullptr, cW2T, out_6,
                                                        s62, q62, C6ROWS);
  bnf_k<<<cdiv(C6ROWS*64,256),256,0,stream>>>(out_6, s62, q62, cg2, cb2, C6ROWS);
}

// Round 6
// 858.346 us; speedup vs baseline: 1.3521x; 1.1400x over previous
//
#include <hip/hip_runtime.h>
#include <hip/hip_bf16.h>

#define NNODES 40000
#define NEDGE  60000
#define NCYC5  30000
#define NCYC6  25000
#define EROWS  (2*NEDGE)    // 120000
#define C5ROWS (5*NCYC5)    // 150000
#define C6ROWS (6*NCYC6)    // 150000

typedef __attribute__((ext_vector_type(8))) short short8;   // 8 bf16 lanes
typedef __attribute__((ext_vector_type(4))) float f32x4;

__device__ __forceinline__ short f2bs(float x){
  union { __hip_bfloat16 h; short s; } u; u.h = __float2bfloat16(x); return u.s;
}
__device__ __forceinline__ float bs2f(short s){
  union { short s; __hip_bfloat16 h; } u; u.s = s; return __bfloat162float(u.h);
}

// accumulate 8 bf16 lanes into two f32x4
__device__ __forceinline__ void acc8(f32x4& lo, f32x4& hi, short8 v){
  #pragma unroll
  for (int j = 0; j < 4; ++j){ lo[j] += bs2f(v[j]); hi[j] += bs2f(v[j+4]); }
}
__device__ __forceinline__ short8 pack8(f32x4 lo, f32x4 hi){
  short8 r;
  #pragma unroll
  for (int j = 0; j < 4; ++j){ r[j] = f2bs(lo[j]); r[j+4] = f2bs(hi[j]); }
  return r;
}

// rows m and m^1 live in adjacent lanes (l15 pairs): piece3 = val(m)+val(m^1)
__device__ __forceinline__ short8 combine_pair(short8 a){
  union U { short8 v; int i[4]; } u, w;
  u.v = a;
  #pragma unroll
  for (int j = 0; j < 4; ++j) w.i[j] = __shfl_xor(u.i[j], 1);
  short8 r;
  #pragma unroll
  for (int j = 0; j < 8; ++j) r[j] = f2bs(bs2f(a[j]) + bs2f(w.v[j]));
  return r;
}

// drain-free barrier: LDS ops must land (lgkmcnt) but global prefetches
// stay IN FLIGHT across the barrier (unlike __syncthreads' vmcnt(0) drain)
__device__ __forceinline__ void lds_barrier(){
  asm volatile("s_waitcnt lgkmcnt(0)" ::: "memory");
  __builtin_amdgcn_s_barrier();
}

// ---------------- CSR build (fused 3-range) ----------------
__global__ void hist3_k(const int* __restrict__ ea, const int* __restrict__ c5a,
                        const int* __restrict__ c6a, int* __restrict__ de,
                        int* __restrict__ d5, int* __restrict__ d6){
  int r = blockIdx.x*256 + threadIdx.x;
  if (r < EROWS)                        atomicAdd(&de[ea[r]], 1);
  else if (r < EROWS + C5ROWS)          atomicAdd(&d5[c5a[r - EROWS]], 1);
  else if (r < EROWS + C5ROWS + C6ROWS) atomicAdd(&d6[c6a[r - EROWS - C5ROWS]], 1);
}

__global__ void scan3_k(const int* __restrict__ d0, const int* __restrict__ d1,
                        const int* __restrict__ d2, int* __restrict__ o0,
                        int* __restrict__ o1, int* __restrict__ o2){
  const int* deg = blockIdx.x==0 ? d0 : (blockIdx.x==1 ? d1 : d2);
  int* offs      = blockIdx.x==0 ? o0 : (blockIdx.x==1 ? o1 : o2);
  const int N = NNODES;
  __shared__ int part[1024];
  int tid = threadIdx.x;
  const int chunk = (N + 1023) / 1024;
  int lo = tid*chunk, hi = min(lo+chunk, N);
  int s = 0;
  for (int i = lo; i < hi; ++i) s += deg[i];
  part[tid] = s;
  __syncthreads();
  for (int d = 1; d < 1024; d <<= 1){
    int v = (tid >= d) ? part[tid-d] : 0;
    __syncthreads();
    part[tid] += v;
    __syncthreads();
  }
  int pref = (tid == 0) ? 0 : part[tid-1];
  for (int i = lo; i < hi; ++i){ offs[i] = pref; pref += deg[i]; }
  if (tid == 1023) offs[N] = part[1023];
}

__global__ void fill3_k(const int* __restrict__ ea, const int* __restrict__ c5a,
                        const int* __restrict__ c6a,
                        const int* __restrict__ oe, const int* __restrict__ o5,
                        const int* __restrict__ o6,
                        int* __restrict__ cue, int* __restrict__ cu5,
                        int* __restrict__ cu6,
                        int* __restrict__ re, int* __restrict__ r5,
                        int* __restrict__ r6){
  int r = blockIdx.x*256 + threadIdx.x;
  if (r < EROWS){
    int a = ea[r]; re[oe[a] + atomicAdd(&cue[a],1)] = r;
  } else if (r < EROWS + C5ROWS){
    int rr = r - EROWS; int a = c5a[rr]; r5[o5[a] + atomicAdd(&cu5[a],1)] = rr;
  } else if (r < EROWS + C5ROWS + C6ROWS){
    int rr = r - EROWS - C5ROWS; int a = c6a[rr]; r6[o6[a] + atomicAdd(&cu6[a],1)] = rr;
  }
}

// ---------------- phase-1 gather kernels (vectorized, unroll-2) ----------------
// All gathers: 4 fp32 or 8 bf16 channels per thread (16B loads), dual
// accumulators on the runtime CSR loops -> 2 loads in flight per lane,
// 4-8x fewer waves than the 1-channel/thread versions (latency-bound fix).

// node_e[n][0:64] = sum over incident edge rows; 16 threads/node (float4)
__global__ void gne_k(const float* __restrict__ ef, const int* __restrict__ offs,
                      const int* __restrict__ rows, float* __restrict__ node_e){
  int t = blockIdx.x*256 + threadIdx.x;
  if (t >= NNODES*16) return;
  int n = t >> 4, q = t & 15;
  int o = offs[n], e = offs[n+1];
  const f32x4* ef4 = (const f32x4*)ef;
  f32x4 s0 = {0,0,0,0}, s1 = {0,0,0,0};
  int i = o;
  for (; i+1 < e; i += 2){
    f32x4 a = ef4[(size_t)rows[i]*16 + q];
    f32x4 b = ef4[(size_t)rows[i+1]*16 + q];
    s0 += a; s1 += b;
  }
  if (i < e) s0 += ef4[(size_t)rows[i]*16 + q];
  ((f32x4*)node_e)[t] = s0 + s1;
}

// S1_5[c] = sum_j node_e[atom5[c*5+j]]; S1_6 likewise; 16 threads/row
__global__ void s1f_k(const float* __restrict__ node_e,
                      const int* __restrict__ a5, const int* __restrict__ a6,
                      float* __restrict__ S1_5, float* __restrict__ S1_6){
  int t = blockIdx.x*256 + threadIdx.x;
  const f32x4* ne4 = (const f32x4*)node_e;
  if (t < NCYC5*16){
    int c = t >> 4, q = t & 15;
    const int* ap = a5 + c*5;
    f32x4 s = {0,0,0,0};
    #pragma unroll
    for (int j = 0; j < 5; ++j) s += ne4[(size_t)ap[j]*16 + q];
    ((f32x4*)S1_5)[t] = s;
  } else if (t < NCYC5*16 + NCYC6*16){
    int t2 = t - NCYC5*16;
    int c = t2 >> 4, q = t2 & 15;
    const int* ap = a6 + c*6;
    f32x4 s = {0,0,0,0};
    #pragma unroll
    for (int j = 0; j < 6; ++j) s += ne4[(size_t)ap[j]*16 + q];
    ((f32x4*)S1_6)[t2] = s;
  }
}

// n5_Xh[n] = [degX(n)*node_e[n] ; CSR-sum of S1_X[r/R]]; 16 threads/node
__global__ void n5f_k(const float* __restrict__ node_e,
                      const int* __restrict__ o5, const int* __restrict__ r5,
                      const int* __restrict__ o6, const int* __restrict__ r6,
                      const float* __restrict__ S1_5, const float* __restrict__ S1_6,
                      short* __restrict__ n5_5h, short* __restrict__ n5_6h){
  int t = blockIdx.x*256 + threadIdx.x;
  if (t >= NNODES*16) return;
  int n = t >> 4, q = t & 15;
  f32x4 v = ((const f32x4*)node_e)[t];
  const f32x4* S54 = (const f32x4*)S1_5;
  const f32x4* S64 = (const f32x4*)S1_6;
  int a5 = o5[n], b5 = o5[n+1], a6 = o6[n], b6 = o6[n+1];
  f32x4 s5a = {0,0,0,0}, s5b = {0,0,0,0}, s6a = {0,0,0,0}, s6b = {0,0,0,0};
  int i = a5;
  for (; i+1 < b5; i += 2){
    s5a += S54[(size_t)(r5[i]/5)*16 + q];
    s5b += S54[(size_t)(r5[i+1]/5)*16 + q];
  }
  if (i < b5) s5a += S54[(size_t)(r5[i]/5)*16 + q];
  i = a6;
  for (; i+1 < b6; i += 2){
    s6a += S64[(size_t)(r6[i]/6)*16 + q];
    s6b += S64[(size_t)(r6[i+1]/6)*16 + q];
  }
  if (i < b6) s6a += S64[(size_t)(r6[i]/6)*16 + q];
  f32x4 s5 = s5a + s5b, s6 = s6a + s6b;
  float d5 = (float)(b5-a5), d6 = (float)(b6-a6);
  short4 w;
  #define ST4(dst, vec) { w.x=f2bs((vec)[0]); w.y=f2bs((vec)[1]); w.z=f2bs((vec)[2]); w.w=f2bs((vec)[3]); *(short4*)(dst) = w; }
  f32x4 lo5 = d5*v, lo6 = d6*v;
  ST4(n5_5h + (size_t)n*128 + q*4, lo5);
  ST4(n5_5h + (size_t)n*128 + 64 + q*4, s5);
  ST4(n5_6h + (size_t)n*128 + q*4, lo6);
  ST4(n5_6h + (size_t)n*128 + 64 + q*4, s6);
  #undef ST4
}

// S2_X[c][ch] = sum_j n5_Xh[atomX[c*R+j]][ch]; 16 threads/row (short8)
__global__ void s2f_k(const short* __restrict__ n5_5h, const short* __restrict__ n5_6h,
                      const int* __restrict__ a5, const int* __restrict__ a6,
                      short* __restrict__ S2_5h, short* __restrict__ S2_6h){
  int t = blockIdx.x*256 + threadIdx.x;
  const short8* n58 = (const short8*)n5_5h;
  const short8* n68 = (const short8*)n5_6h;
  if (t < NCYC5*16){
    int c = t >> 4, q = t & 15;
    const int* ap = a5 + c*5;
    f32x4 lo = {0,0,0,0}, hi = {0,0,0,0};
    #pragma unroll
    for (int j = 0; j < 5; ++j) acc8(lo, hi, n58[(size_t)ap[j]*16 + q]);
    ((short8*)S2_5h)[t] = pack8(lo, hi);
  } else if (t < NCYC5*16 + NCYC6*16){
    int t2 = t - NCYC5*16;
    int c = t2 >> 4, q = t2 & 15;
    const int* ap = a6 + c*6;
    f32x4 lo = {0,0,0,0}, hi = {0,0,0,0};
    #pragma unroll
    for (int j = 0; j < 6; ++j) acc8(lo, hi, n68[(size_t)ap[j]*16 + q]);
    ((short8*)S2_6h)[t2] = pack8(lo, hi);
  }
}

// nodeC[n][0:320] one pass; thread space [piece1:16t/n][piece2:16t/n][piece3:8t/n]
// so branch regions stay wave-uniform. short8 / 2xfloat4 per thread.
__global__ void ncf_k(const short* __restrict__ n5_5h, const short* __restrict__ n5_6h,
                      const int* __restrict__ o5, const int* __restrict__ r5,
                      const int* __restrict__ o6, const int* __restrict__ r6,
                      const short* __restrict__ S2_5h, const short* __restrict__ S2_6h,
                      const float* __restrict__ c5f, const float* __restrict__ c6f,
                      short* __restrict__ nodeC){
  int t = blockIdx.x*256 + threadIdx.x;
  short8* nc8 = (short8*)nodeC;                 // row stride 40 short8
  if (t < NNODES*16){
    // piece 1: ch 0..127 = d5*n5_5 + d6*n5_6
    int n = t >> 4, q = t & 15;
    short8 a = ((const short8*)n5_5h)[(size_t)n*16 + q];
    short8 b = ((const short8*)n5_6h)[(size_t)n*16 + q];
    float d5 = (float)(o5[n+1]-o5[n]), d6 = (float)(o6[n+1]-o6[n]);
    short8 r;
    #pragma unroll
    for (int j = 0; j < 8; ++j) r[j] = f2bs(d5*bs2f(a[j]) + d6*bs2f(b[j]));
    nc8[(size_t)n*40 + q] = r;
  } else if (t < NNODES*32){
    // piece 2: ch 128..255 = CSR-sum of S2 rows
    int t2 = t - NNODES*16;
    int n = t2 >> 4, q = t2 & 15;
    const short8* S58 = (const short8*)S2_5h;
    const short8* S68 = (const short8*)S2_6h;
    f32x4 lo0 = {0,0,0,0}, hi0 = {0,0,0,0}, lo1 = {0,0,0,0}, hi1 = {0,0,0,0};
    int i = o5[n], e = o5[n+1];
    for (; i+1 < e; i += 2){
      acc8(lo0, hi0, S58[(size_t)(r5[i]/5)*16 + q]);
      acc8(lo1, hi1, S58[(size_t)(r5[i+1]/5)*16 + q]);
    }
    if (i < e) acc8(lo0, hi0, S58[(size_t)(r5[i]/5)*16 + q]);
    i = o6[n]; e = o6[n+1];
    for (; i+1 < e; i += 2){
      acc8(lo0, hi0, S68[(size_t)(r6[i]/6)*16 + q]);
      acc8(lo1, hi1, S68[(size_t)(r6[i+1]/6)*16 + q]);
    }
    if (i < e) acc8(lo0, hi0, S68[(size_t)(r6[i]/6)*16 + q]);
    nc8[(size_t)n*40 + 16 + q] = pack8(lo0 + lo1, hi0 + hi1);
  } else if (t < NNODES*40){
    // piece 3: ch 256..319 = CSR-sum of cycle feats (fp32 source)
    int t3 = t - NNODES*32;
    int n = t3 >> 3, q = t3 & 7;
    const f32x4* c54 = (const f32x4*)c5f;       // row stride 16 f32x4
    const f32x4* c64 = (const f32x4*)c6f;
    f32x4 s0 = {0,0,0,0}, s1 = {0,0,0,0}, s2 = {0,0,0,0}, s3 = {0,0,0,0};
    int i = o5[n], e = o5[n+1];
    for (; i+1 < e; i += 2){
      size_t ra = (size_t)r5[i]*16 + q*2, rb = (size_t)r5[i+1]*16 + q*2;
      s0 += c54[ra]; s2 += c54[ra+1];
      s1 += c54[rb]; s3 += c54[rb+1];
    }
    if (i < e){ size_t ra = (size_t)r5[i]*16 + q*2; s0 += c54[ra]; s2 += c54[ra+1]; }
    i = o6[n]; e = o6[n+1];
    for (; i+1 < e; i += 2){
      size_t ra = (size_t)r6[i]*16 + q*2, rb = (size_t)r6[i+1]*16 + q*2;
      s0 += c64[ra]; s2 += c64[ra+1];
      s1 += c64[rb]; s3 += c64[rb+1];
    }
    if (i < e){ size_t ra = (size_t)r6[i]*16 + q*2; s0 += c64[ra]; s2 += c64[ra+1]; }
    nc8[(size_t)n*40 + 32 + q] = pack8(s0 + s1, s2 + s3);
  }
}

__global__ void f2h3_k(const float* __restrict__ e, const float* __restrict__ c5,
                       const float* __restrict__ c6, short* __restrict__ eh,
                       short* __restrict__ c5h, short* __restrict__ c6h){
  int t = blockIdx.x*256 + threadIdx.x;
  const float* s; short* d; int i;
  if (t < EROWS*16)                        { s=e;  d=eh;  i=t; }
  else if (t < EROWS*16 + C5ROWS*16)       { s=c5; d=c5h; i=t - EROWS*16; }
  else if (t < EROWS*16 + C5ROWS*16 + C6ROWS*16) { s=c6; d=c6h; i=t - EROWS*16 - C5ROWS*16; }
  else return;
  float4 v = ((const float4*)s)[i];
  short4 o; o.x=f2bs(v.x); o.y=f2bs(v.y); o.z=f2bs(v.z); o.w=f2bs(v.w);
  ((short4*)d)[i] = o;
}

__global__ void tr4_k(const float* __restrict__ eW1, const float* __restrict__ cW1,
                      const float* __restrict__ eW2, const float* __restrict__ cW2,
                      short* __restrict__ eW1T, short* __restrict__ cW1T,
                      short* __restrict__ eW2T, short* __restrict__ cW2T){
  int t = blockIdx.x*256 + threadIdx.x;
  if (t < 704*128){
    int k = t >> 7, n = t & 127; eW1T[(size_t)n*704 + k] = f2bs(eW1[t]);
  } else if (t < 704*128 + 320*128){
    int t2 = t - 704*128; int k = t2 >> 7, n = t2 & 127;
    cW1T[(size_t)n*320 + k] = f2bs(cW1[t2]);
  } else if (t < 704*128 + 320*128 + 128*64){
    int t3 = t - 704*128 - 320*128; int k = t3 >> 6, n = t3 & 63;
    eW2T[(size_t)n*128 + k] = f2bs(eW2[t3]);
  } else if (t < 704*128 + 320*128 + 2*128*64){
    int t4 = t - 704*128 - 320*128 - 128*64; int k = t4 >> 6, n = t4 & 63;
    cW2T[(size_t)n*128 + k] = f2bs(cW2[t4]);
  }
}

// final BatchNorm+ReLU on fp32 d_out (C=64), in place
__global__ void bnf_k(float* __restrict__ X, const float* __restrict__ ssum,
                      const float* __restrict__ ssq, const float* __restrict__ g,
                      const float* __restrict__ b, int M){
  int t = blockIdx.x*256 + threadIdx.x;
  if (t >= M*64) return;
  int ch = t & 63;
  float inv  = 1.f / (float)M;
  float mean = ssum[ch]*inv;
  float var  = fmaxf(ssq[ch]*inv - mean*mean, 0.f);
  float sc   = g[ch] * rsqrtf(var + 1e-5f);
  X[t] = fmaxf(sc*X[t] + (b[ch] - mean*sc), 0.f);
}

// ---------------- MFMA GEMM: LDS B-staging + drain-free barriers ----------------
// (validated at round 5: gemm_k no longer in top-5 dispatches; unchanged)
// LOADER 1: edge rows  [ef_h(64) | nodeC_h[aS](320) | shfl-combined(320)], KC=704
// LOADER 2: cycle rows [n5h[aS](128) | S2h[m/RDIV](128) | featsh(64)],    KC=320
// LOADER 3: bf16 A + inline BN1 affine+ReLU from layer-1 stats
//           (G0=ssum_in fp32, G1=ssq_in fp32, F0=gamma, F1=beta), KC=128
template<int LOADER, int NT, int OUTF32, int KC, int RDIV>
__global__ __launch_bounds__(256) void gemm_k(
    const short* __restrict__ A, const short* __restrict__ G0,
    const short* __restrict__ G1, const float* __restrict__ F0,
    const float* __restrict__ F1, const int* __restrict__ atoms,
    const short* __restrict__ BT, void* __restrict__ CoutV,
    float* __restrict__ ssum, float* __restrict__ ssq, int M)
{
  constexpr int NK = KC/32;          // k-slices
  static_assert(NK % 2 == 0, "final MFMA must read LDS buffer 1 (sred aliases buffer 0)");
  constexpr int NC = NT*16;          // output cols = BT rows staged
  constexpr int CH = (NC*4)/256;     // 16B chunks per thread per slice
  __shared__ short lds[2*NC*32];     // 2 slice buffers

  const int wv   = threadIdx.x >> 6;
  const int lane = threadIdx.x & 63;
  const int row0 = blockIdx.x*64 + wv*16;
  const int l15 = lane & 15, quad = lane >> 4;
  const bool act = (row0 < M);
  const int m = act ? (row0 + l15) : 0;

  int aS = 0, cyc = 0;
  if (LOADER == 1) aS = act ? atoms[m] : 0;
  if (LOADER == 2) { aS = act ? atoms[m] : 0; cyc = m / RDIV; }

  constexpr int NLD = (LOADER==1) ? 12 : (LOADER==2 ? 10 : NK);
  short8 af[NLD];
  if (act) {
    #pragma unroll
    for (int kt = 0; kt < NLD; ++kt) {
      const int k0 = kt*32 + quad*8;
      if (LOADER == 1) {
        if (kt < 2) af[kt] = *reinterpret_cast<const short8*>(A + (size_t)m*64 + k0);
        else        af[kt] = *reinterpret_cast<const short8*>(G0 + (size_t)aS*320 + (k0-64));
      } else if (LOADER == 2) {
        if (kt < 4)      af[kt] = *reinterpret_cast<const short8*>(G0 + (size_t)aS*128 + k0);
        else if (kt < 8) af[kt] = *reinterpret_cast<const short8*>(G1 + (size_t)cyc*128 + (k0-128));
        else             af[kt] = *reinterpret_cast<const short8*>(A + (size_t)m*64 + (k0-256));
      } else {
        af[kt] = *reinterpret_cast<const short8*>(A + (size_t)m*KC + k0);
      }
    }
  }

  auto stage_load = [&](int kt, short8* r){
    #pragma unroll
    for (int i = 0; i < CH; ++i) {
      int id = i*256 + (int)threadIdx.x;        // chunk id: n = id>>2, c = id&3
      r[i] = *reinterpret_cast<const short8*>(BT + (size_t)(id>>2)*KC + kt*32 + (id&3)*8);
    }
  };
  auto stage_write = [&](int b, short8* r){
    #pragma unroll
    for (int i = 0; i < CH; ++i) {
      int id = i*256 + (int)threadIdx.x;
      int n = id>>2, c = id&3;
      *reinterpret_cast<short8*>(&lds[b*NC*32 + n*32 + ((c ^ ((n>>1)&3)))*8]) = r[i];
    }
  };

  f32x4 acc[NT];
  #pragma unroll
  for (int nt = 0; nt < NT; ++nt) acc[nt] = (f32x4){0.f,0.f,0.f,0.f};

  short8 sr0[CH], sr1[CH], sr2[CH];
  stage_load(0, sr0);
  if (NK > 1) stage_load(1, sr1);

  const float invM = 1.f / (float)M;

  #pragma unroll
  for (int kt = 0; kt < NK; ++kt) {
    short8* cur = (kt % 3 == 0) ? sr0 : ((kt % 3 == 1) ? sr1 : sr2);
    stage_write(kt & 1, cur);
    if (kt + 2 < NK) {
      short8* nxt = ((kt+2) % 3 == 0) ? sr0 : (((kt+2) % 3 == 1) ? sr1 : sr2);
      stage_load(kt + 2, nxt);
    }
    lds_barrier();

    if (act) {
      const int k0 = kt*32 + quad*8;
      short8 afk;
      {
        short8 base = af[(kt < NLD) ? kt : (kt - 10)];
        if (LOADER == 3) {
          const float* ssin = reinterpret_cast<const float*>(G0);
          const float* qqin = reinterpret_cast<const float*>(G1);
          float ssv[8], qqv[8], gv[8], bv[8];
          *reinterpret_cast<float4*>(&ssv[0]) = *reinterpret_cast<const float4*>(ssin + k0);
          *reinterpret_cast<float4*>(&ssv[4]) = *reinterpret_cast<const float4*>(ssin + k0 + 4);
          *reinterpret_cast<float4*>(&qqv[0]) = *reinterpret_cast<const float4*>(qqin + k0);
          *reinterpret_cast<float4*>(&qqv[4]) = *reinterpret_cast<const float4*>(qqin + k0 + 4);
          *reinterpret_cast<float4*>(&gv[0])  = *reinterpret_cast<const float4*>(F0 + k0);
          *reinterpret_cast<float4*>(&gv[4])  = *reinterpret_cast<const float4*>(F0 + k0 + 4);
          *reinterpret_cast<float4*>(&bv[0])  = *reinterpret_cast<const float4*>(F1 + k0);
          *reinterpret_cast<float4*>(&bv[4])  = *reinterpret_cast<const float4*>(F1 + k0 + 4);
          #pragma unroll
          for (int j = 0; j < 8; ++j) {
            float mean = ssv[j]*invM;
            float var  = fmaxf(qqv[j]*invM - mean*mean, 0.f);
            float sc   = gv[j] * rsqrtf(var + 1e-5f);
            float sh   = bv[j] - mean*sc;
            afk[j] = f2bs(fmaxf(sc*bs2f(base[j]) + sh, 0.f));
          }
        } else if (LOADER == 1 && kt >= 12) {
          afk = combine_pair(base);
        } else {
          afk = base;
        }
      }
      #pragma unroll
      for (int nt = 0; nt < NT; ++nt) {
        const int n = nt*16 + l15;
        const short8 bfg = *reinterpret_cast<const short8*>(
            &lds[(kt&1)*NC*32 + n*32 + ((quad ^ ((n>>1)&3)))*8]);
        acc[nt] = __builtin_amdgcn_mfma_f32_16x16x32_bf16(afk, bfg, acc[nt], 0, 0, 0);
      }
    }
  }

  float* sred = reinterpret_cast<float*>(lds);

  #pragma unroll
  for (int nt = 0; nt < NT; ++nt) {
    float ps = 0.f, pq = 0.f;
    if (act) {
      #pragma unroll
      for (int rg = 0; rg < 4; ++rg) {
        float v = acc[nt][rg];                     // D[row=quad*4+rg][col=l15]
        int r = row0 + quad*4 + rg;
        if (OUTF32) ((float*)CoutV)[(size_t)r*NC + nt*16 + l15] = v;
        else        ((short*)CoutV)[(size_t)r*NC + nt*16 + l15] = f2bs(v);
        ps += v; pq += v*v;
      }
    }
    ps += __shfl_xor(ps, 16); pq += __shfl_xor(pq, 16);
    ps += __shfl_xor(ps, 32); pq += __shfl_xor(pq, 32);
    if (lane < 16) {                               // quad == 0
      sred[wv*NC + nt*16 + lane]        = ps;
      sred[4*NC + wv*NC + nt*16 + lane] = pq;
    }
  }
  __syncthreads();
  for (int ch = threadIdx.x; ch < NC; ch += 256) {
    float s = sred[ch] + sred[NC + ch] + sred[2*NC + ch] + sred[3*NC + ch];
    float q = sred[4*NC + ch] + sred[5*NC + ch] + sred[6*NC + ch] + sred[7*NC + ch];
    atomicAdd(&ssum[ch], s);
    atomicAdd(&ssq[ch], q);
  }
}

static inline int cdiv(int a, int b){ return (a + b - 1)/b; }

extern "C" void kernel_launch(void* const* d_in, const int* in_sizes, int n_in,
                              void* d_out, int out_size, void* d_ws, size_t ws_size,
                              hipStream_t stream)
{
  const float* edge_feats = (const float*)d_in[0];
  const float* c5_feats   = (const float*)d_in[1];
  const float* c6_feats   = (const float*)d_in[2];
  const int*   e_atoms    = (const int*)d_in[3];
  const int*   c5_atoms   = (const int*)d_in[4];
  const int*   c6_atoms   = (const int*)d_in[5];
  const float* eW1 = (const float*)d_in[6];
  const float* eg1 = (const float*)d_in[7];
  const float* eb1 = (const float*)d_in[8];
  const float* eW2 = (const float*)d_in[9];
  const float* eg2 = (const float*)d_in[10];
  const float* eb2 = (const float*)d_in[11];
  const float* cW1 = (const float*)d_in[12];
  const float* cg1 = (const float*)d_in[13];
  const float* cb1 = (const float*)d_in[14];
  const float* cW2 = (const float*)d_in[15];
  const float* cg2 = (const float*)d_in[16];
  const float* cb2 = (const float*)d_in[17];
  float* out = (float*)d_out;
  (void)in_sizes; (void)n_in; (void)out_size; (void)ws_size;

  char* w = (char*)d_ws;
  auto alloc = [&](size_t bytes) -> char* {
    char* p = w; w += (bytes + 255) & ~(size_t)255; return p;
  };

  // ---- zero zone (~1 MB): histograms, cursors, stats ----
  char* zbase = w;
  int*  deg_e = (int*)alloc(NNODES*4);
  int*  deg_5 = (int*)alloc(NNODES*4);
  int*  deg_6 = (int*)alloc(NNODES*4);
  int*  cur_e = (int*)alloc(NNODES*4);
  int*  cur_5 = (int*)alloc(NNODES*4);
  int*  cur_6 = (int*)alloc(NNODES*4);
  float* stats = (float*)alloc(1152*4);
  size_t zbytes = (size_t)(w - zbase);

  float* se1 = stats;        float* qe1 = stats + 128;
  float* se2 = stats + 256;  float* qe2 = stats + 320;
  float* s51 = stats + 384;  float* q51 = stats + 512;
  float* s52 = stats + 640;  float* q52 = stats + 704;
  float* s61 = stats + 768;  float* q61 = stats + 896;
  float* s62 = stats + 1024; float* q62 = stats + 1088;

  // ---- write-before-read buffers ----
  int* offs_e = (int*)alloc((NNODES+1)*4);
  int* offs_5 = (int*)alloc((NNODES+1)*4);
  int* offs_6 = (int*)alloc((NNODES+1)*4);
  int* rows_e = (int*)alloc((size_t)EROWS*4);
  int* rows_5 = (int*)alloc((size_t)C5ROWS*4);
  int* rows_6 = (int*)alloc((size_t)C6ROWS*4);
  short* nodeC_h = (short*)alloc((size_t)NNODES*320*2);   // 25.6 MB
  short* n5_5h   = (short*)alloc((size_t)NNODES*128*2);   // 10.24 MB
  short* n5_6h   = (short*)alloc((size_t)NNODES*128*2);
  short* S2_5h   = (short*)alloc((size_t)NCYC5*128*2);    // 7.68 MB
  short* S2_6h   = (short*)alloc((size_t)NCYC6*128*2);    // 6.4 MB
  short* ef_h    = (short*)alloc((size_t)EROWS*64*2);     // 15.36 MB
  short* c5f_h   = (short*)alloc((size_t)C5ROWS*64*2);    // 19.2 MB
  short* c6f_h   = (short*)alloc((size_t)C6ROWS*64*2);    // 19.2 MB
  short* eW1T    = (short*)alloc((size_t)128*704*2);
  short* cW1T    = (short*)alloc((size_t)128*320*2);
  short* eW2T    = (short*)alloc((size_t)64*128*2);
  short* cW2T    = (short*)alloc((size_t)64*128*2);
  // h1 region (38.4 MB) shared by 3 MLPs; phase-1 fp32 temporaries alias it
  char*  h1reg = alloc((size_t)C5ROWS*128*2);
  short* h1    = (short*)h1reg;
  float* node_e = (float*)h1reg;                                          // 10.24 MB
  float* S1_5   = (float*)(h1reg + (size_t)NNODES*64*4);                  // 7.68 MB
  float* S1_6   = (float*)(h1reg + (size_t)NNODES*64*4 + (size_t)NCYC5*64*4); // 6.4 MB

  hipMemsetAsync(zbase, 0, zbytes, stream);

  // ---- CSR build (fused) ----
  const int TOTROWS = EROWS + C5ROWS + C6ROWS;
  hist3_k<<<cdiv(TOTROWS,256),256,0,stream>>>(e_atoms, c5_atoms, c6_atoms,
                                              deg_e, deg_5, deg_6);
  scan3_k<<<3,1024,0,stream>>>(deg_e, deg_5, deg_6, offs_e, offs_5, offs_6);
  fill3_k<<<cdiv(TOTROWS,256),256,0,stream>>>(e_atoms, c5_atoms, c6_atoms,
                                              offs_e, offs_5, offs_6,
                                              cur_e, cur_5, cur_6,
                                              rows_e, rows_5, rows_6);

  // ---- bf16 copies + weight transposes (fused) ----
  f2h3_k<<<cdiv((EROWS+C5ROWS+C6ROWS)*16,256),256,0,stream>>>(
      edge_feats, c5_feats, c6_feats, ef_h, c5f_h, c6f_h);
  tr4_k<<<cdiv(704*128 + 320*128 + 2*128*64,256),256,0,stream>>>(
      eW1, cW1, eW2, cW2, eW1T, cW1T, eW2T, cW2T);

  // ---- phase 1: node/cycle aggregates (vectorized gathers) ----
  gne_k<<<cdiv(NNODES*16,256),256,0,stream>>>(edge_feats, offs_e, rows_e, node_e);
  s1f_k<<<cdiv(NCYC5*16 + NCYC6*16,256),256,0,stream>>>(node_e, c5_atoms, c6_atoms,
                                                        S1_5, S1_6);
  n5f_k<<<cdiv(NNODES*16,256),256,0,stream>>>(node_e, offs_5, rows_5, offs_6, rows_6,
                                              S1_5, S1_6, n5_5h, n5_6h);
  s2f_k<<<cdiv(NCYC5*16 + NCYC6*16,256),256,0,stream>>>(n5_5h, n5_6h,
                                                        c5_atoms, c6_atoms,
                                                        S2_5h, S2_6h);
  ncf_k<<<cdiv(NNODES*40,256),256,0,stream>>>(n5_5h, n5_6h, offs_5, rows_5,
                                              offs_6, rows_6, S2_5h, S2_6h,
                                              c5_feats, c6_feats, nodeC_h);

  float* out_e = out;
  float* out_5 = out + (size_t)EROWS*64;
  float* out_6 = out + (size_t)(EROWS + C5ROWS)*64;

  // ---- edge MLP ----
  gemm_k<1,8,0,704,1><<<cdiv(EROWS,64),256,0,stream>>>(ef_h, nodeC_h, nullptr, nullptr, nullptr,
                                                       e_atoms, eW1T, h1, se1, qe1, EROWS);
  gemm_k<3,4,1,128,1><<<cdiv(EROWS,64),256,0,stream>>>(h1, (const short*)se1, (const short*)qe1,
                                                       eg1, eb1, nullptr, eW2T, out_e,
                                                       se2, qe2, EROWS);
  bnf_k<<<cdiv(EROWS*64,256),256,0,stream>>>(out_e, se2, qe2, eg2, eb2, EROWS);

  // ---- cycle5 MLP ----
  gemm_k<2,8,0,320,5><<<cdiv(C5ROWS,64),256,0,stream>>>(c5f_h, n5_5h, S2_5h, nullptr, nullptr,
                                                        c5_atoms, cW1T, h1, s51, q51, C5ROWS);
  gemm_k<3,4,1,128,1><<<cdiv(C5ROWS,64),256,0,stream>>>(h1, (const short*)s51, (const short*)q51,
                                                        cg1, cb1, nullptr, cW2T, out_5,
                                                        s52, q52, C5ROWS);
  bnf_k<<<cdiv(C5ROWS*64,256),256,0,stream>>>(out_5, s52, q52, cg2, cb2, C5ROWS);

  // ---- cycle6 MLP ----
  gemm_k<2,8,0,320,6><<<cdiv(C6ROWS,64),256,0,stream>>>(c6f_h, n5_6h, S2_6h, nullptr, nullptr,
                                                        c6_atoms, cW1T, h1, s61, q61, C6ROWS);
  gemm_k<3,4,1,128,1><<<cdiv(C6ROWS,64),256,0,stream>>>(h1, (const short*)s61, (const short*)q61,
                                                        cg1, cb1, nullptr, cW2T, out_6,
                                                        s62, q62, C6ROWS);
  bnf_k<<<cdiv(C6ROWS*64,256),256,0,stream>>>(out_6, s62, q62, cg2, cb2, C6ROWS);
}